// Round 1
// baseline (1134.357 us; speedup 1.0000x reference)
//
#include <hip/hip_runtime.h>
#include <hip/hip_fp16.h>

typedef unsigned int  uint;
typedef unsigned short ushort;

#define NW       16384            // words in sentence
#define HID_BASE (50*16384)       // d_out: [0,HID_BASE) = logp[t][s], then hidden[s][384]

// ---------- helpers ----------
__device__ __forceinline__ __half2 hfma2u(uint a, uint b, __half2 acc) {
    return __hfma2(__builtin_bit_cast(__half2, a), __builtin_bit_cast(__half2, b), acc);
}
__device__ __forceinline__ float h2sum(__half2 v) { return __low2float(v) + __high2float(v); }
__device__ __forceinline__ uint packf16(float a, float b) {
    __half2 v = __floats2half2_rn(a, b);
    return __builtin_bit_cast(uint, v);
}
__device__ __forceinline__ float sig_(float x)  { return 1.0f / (1.0f + __expf(-x)); }
__device__ __forceinline__ float tanh_(float x) {
    x = fminf(fmaxf(x, -30.f), 30.f);
    float e = __expf(2.f * x);
    return (e - 1.f) / (e + 1.f);
}

// ---------- K1: prep (E table, f16 weight repacks, lin_W transpose) ----------
// sections (flat gid):
//  A: 65536  E'[c][uu*4+gs] = relu(cemb[c]) . wih_c[gate] + bihc+bhhc,  gate = gs*128+uu
//  B: 32768  Wch[uu][kk][gs] f16-pair of whh_c[gs*128+uu][2kk..]
//  C: 65536  Wihw[r][kk]     f16-pair of wih_w[r][2kk..]
//  D: 131072 word whh f16 pairs, split into reg blob [j<96][1024] + lds blob
//  E: 19968  wlin[k][52] = lin_W[t][k] transposed (pad to 52)
__global__ __launch_bounds__(256) void pos_prep(
    const float* __restrict__ cemb,  const float* __restrict__ wihc,
    const float* __restrict__ whhc,  const float* __restrict__ bihc,
    const float* __restrict__ bhhc,  const float* __restrict__ wihw,
    const float* __restrict__ whhw,  const float* __restrict__ linW,
    float* __restrict__ Ep, uint* __restrict__ Wch, uint* __restrict__ Wihw,
    uint* __restrict__ WwR, uint* __restrict__ WwL, float* __restrict__ wlin)
{
    int gid = blockIdx.x * 256 + threadIdx.x;
    if (gid < 65536) {
        int c = gid >> 9, p = gid & 511;
        int uu = p >> 2, gs = p & 3;
        int gate = gs * 128 + uu;
        float acc = bihc[gate] + bhhc[gate];
        const float* er = cemb + c * 64;
        const float* wr = wihc + gate * 64;
        #pragma unroll 16
        for (int k = 0; k < 64; ++k) acc += fmaxf(er[k], 0.f) * wr[k];
        Ep[c * 512 + p] = acc;
        return;
    }
    gid -= 65536;
    if (gid < 32768) {
        int uu = gid >> 8, kk = (gid >> 2) & 63, gs = gid & 3;
        int row = gs * 128 + uu;
        Wch[gid] = packf16(whhc[row * 128 + 2 * kk], whhc[row * 128 + 2 * kk + 1]);
        return;
    }
    gid -= 32768;
    if (gid < 65536) {
        int r = gid >> 6, kk = gid & 63;
        Wihw[gid] = packf16(wihw[r * 128 + 2 * kk], wihw[r * 128 + 2 * kk + 1]);
        return;
    }
    gid -= 65536;
    if (gid < 131072) {
        int j = gid >> 10, t = gid & 1023;
        int q = t >> 9, rb = t & 511;
        int row = (j < 64) ? rb : (512 + rb);
        int kk = j & 63;
        int k0 = q * 128 + 2 * kk;
        uint val = packf16(whhw[row * 256 + k0], whhw[row * 256 + k0 + 1]);
        if (j < 96) WwR[j * 1024 + t] = val;
        else { int jj = j - 96; WwL[((jj >> 2) * 1024 + t) * 4 + (jj & 3)] = val; }
        return;
    }
    gid -= 131072;
    if (gid < 384 * 52) {
        int k = gid / 52, tt = gid % 52;
        wlin[gid] = (tt < 50) ? linW[tt * 384 + k] : 0.f;
    }
}

// ---------- K2: char LSTM ----------
// 256 WGs x 1024 thr (16 waves). WG = 64 words (lane = word), wave owns 8 hidden units.
// gates init from E-table gather; h-GEMM via hfma2 with wave-uniform (scalar) weights.
__global__ __launch_bounds__(1024) void pos_char(
    const int* __restrict__ char_ids, const int* __restrict__ char_lens,
    const float* __restrict__ Ep, const uint* __restrict__ Wch,
    float* __restrict__ out)
{
    __shared__ __align__(16) ushort h_lds[64 * 130]; // row stride 130 (65 dwords, odd -> 2-way max)
    __shared__ float c_lds[64 * 129];
    const int tid  = threadIdx.x;
    const int lane = tid & 63;
    const int wv   = __builtin_amdgcn_readfirstlane(tid >> 6); // 0..15, SGPR
    const int word = blockIdx.x * 64 + lane;
    for (int i = tid; i < 64 * 130; i += 1024) h_lds[i] = 0;
    for (int i = tid; i < 64 * 129; i += 1024) c_lds[i] = 0.f;
    const int len1 = char_lens[word] - 1;
    uint hreg[64];
    #pragma unroll
    for (int j = 0; j < 64; ++j) hreg[j] = 0;
    __syncthreads();
    const uint4* Wq = (const uint4*)Wch;
    const __half2 hz = __float2half2_rn(0.f);
    for (int step = 0; step < 16; ++step) {
        const int cid = char_ids[word * 16 + step];
        const float4* Er = (const float4*)Ep + cid * 128 + wv * 8;
        #pragma unroll
        for (int u = 0; u < 8; ++u) {
            const float4 e = Er[u];
            const int uu = wv * 8 + u;
            const uint4* wrow = Wq + uu * 64;  // uniform -> s_load
            __half2 ai = hz, af = hz, ag = hz, ao = hz;
            #pragma unroll
            for (int kk = 0; kk < 64; ++kk) {
                uint4 w4 = wrow[kk];
                uint hp = hreg[kk];
                ai = hfma2u(hp, w4.x, ai);
                af = hfma2u(hp, w4.y, af);
                ag = hfma2u(hp, w4.z, ag);
                ao = hfma2u(hp, w4.w, ao);
            }
            float gi = e.x + h2sum(ai);
            float gf = e.y + h2sum(af);
            float gg = e.z + h2sum(ag);
            float go = e.w + h2sum(ao);
            float c = c_lds[lane * 129 + uu];
            c = sig_(gf) * c + sig_(gi) * tanh_(gg);
            float h = sig_(go) * tanh_(c);
            c_lds[lane * 129 + uu] = c;
            h_lds[lane * 130 + uu] = __builtin_bit_cast(ushort, (_Float16)h);
            if (step == len1) out[HID_BASE + word * 384 + 256 + uu] = h;
        }
        __syncthreads();
        const uint* hrow = (const uint*)h_lds + lane * 65;
        #pragma unroll
        for (int j = 0; j < 64; ++j) hreg[j] = hrow[j];
        __syncthreads();
    }
}

// ---------- K3: word x-part GEMM: Xw[s][r] = relu(wemb[sent[s]]).wih_w[r] + bihw+bhhw ----------
__global__ __launch_bounds__(1024) void pos_wordx(
    const int* __restrict__ sentence, const float* __restrict__ wemb,
    const uint* __restrict__ Wihw, const float* __restrict__ bihw,
    const float* __restrict__ bhhw, ushort* __restrict__ Xw)
{
    const int tid  = threadIdx.x;
    const int lane = tid & 63;
    const int wv   = __builtin_amdgcn_readfirstlane(tid >> 6); // 0..15, gates wv*64..+64
    const int word = blockIdx.x * 64 + lane;
    const int sid  = sentence[word];
    const float4* xr = (const float4*)(wemb + sid * 128);
    uint xp[64];
    #pragma unroll
    for (int i = 0; i < 32; ++i) {
        float4 v = xr[i];
        xp[2 * i]     = packf16(fmaxf(v.x, 0.f), fmaxf(v.y, 0.f));
        xp[2 * i + 1] = packf16(fmaxf(v.z, 0.f), fmaxf(v.w, 0.f));
    }
    const uint4* Wq = (const uint4*)Wihw;
    const __half2 hz = __float2half2_rn(0.f);
    for (int rr = 0; rr < 64; ++rr) {
        const int r = wv * 64 + rr;
        const uint4* wrow = Wq + r * 16;  // uniform
        __half2 a = hz;
        #pragma unroll
        for (int k4 = 0; k4 < 16; ++k4) {
            uint4 w4 = wrow[k4];
            a = hfma2u(xp[4 * k4 + 0], w4.x, a);
            a = hfma2u(xp[4 * k4 + 1], w4.y, a);
            a = hfma2u(xp[4 * k4 + 2], w4.z, a);
            a = hfma2u(xp[4 * k4 + 3], w4.w, a);
        }
        float acc = bihw[r] + bhhw[r] + h2sum(a);
        Xw[word * 1024 + r] = __builtin_bit_cast(ushort, (_Float16)acc);
    }
}

// ---------- K4: word LSTM, chunk-parallel with 64-step warmup ----------
// 256 WGs x 1024 thr. WG b: outputs steps [64b,64b+64), starts at max(0,64b-64) from zero state.
// thread t: q=t>>9 (k-half), rows rA=t&511, rB=512+rA. Weights: 96 VGPR dwords + 8 LDS uint4.
__global__ __launch_bounds__(1024) void pos_word(
    const ushort* __restrict__ Xw, const uint* __restrict__ WwR,
    const uint4* __restrict__ WwL, float* __restrict__ out)
{
    __shared__ uint4 wlds[8 * 1024];   // 128 KB
    __shared__ float part[2048];       // 8 KB
    __shared__ __align__(16) uint hpq[128]; // h as 128 f16-pairs
    const int t  = threadIdx.x;
    const int q  = __builtin_amdgcn_readfirstlane(t >> 9);
    const int rb = t & 511;
    const int rA = rb, rB = 512 + rb;
    uint wr[96];
    #pragma unroll
    for (int j = 0; j < 96; ++j) wr[j] = WwR[j * 1024 + t];
    #pragma unroll
    for (int g = 0; g < 8; ++g) wlds[g * 1024 + t] = WwL[g * 1024 + t];
    if (t < 128) hpq[t] = 0;
    float c = 0.f;
    __syncthreads();
    const int out_start = blockIdx.x * 64;
    const int s0   = (out_start >= 64) ? (out_start - 64) : 0;
    const int send = out_start + 64;
    const uint4* hq = (const uint4*)hpq + q * 16;
    const __half2 hz = __float2half2_rn(0.f);
    for (int s = s0; s < send; ++s) {
        float xA = 0.f, xB = 0.f;
        if (q == 0) {
            xA = (float)__builtin_bit_cast(_Float16, Xw[s * 1024 + rA]);
            xB = (float)__builtin_bit_cast(_Float16, Xw[s * 1024 + rB]);
        }
        __half2 aA = hz, aB = hz;
        #pragma unroll
        for (int i = 0; i < 8; ++i) {          // rB weights from VGPR
            uint4 hv = hq[i];
            aA = hfma2u(hv.x, wr[4 * i + 0], aA); aA = hfma2u(hv.y, wr[4 * i + 1], aA);
            aA = hfma2u(hv.z, wr[4 * i + 2], aA); aA = hfma2u(hv.w, wr[4 * i + 3], aA);
            aB = hfma2u(hv.x, wr[64 + 4 * i + 0], aB); aB = hfma2u(hv.y, wr[64 + 4 * i + 1], aB);
            aB = hfma2u(hv.z, wr[64 + 4 * i + 2], aB); aB = hfma2u(hv.w, wr[64 + 4 * i + 3], aB);
        }
        #pragma unroll
        for (int i = 8; i < 16; ++i) {         // rB weights from LDS
            uint4 hv = hq[i];
            uint4 w4 = wlds[(i - 8) * 1024 + t];
            aA = hfma2u(hv.x, wr[4 * i + 0], aA); aA = hfma2u(hv.y, wr[4 * i + 1], aA);
            aA = hfma2u(hv.z, wr[4 * i + 2], aA); aA = hfma2u(hv.w, wr[4 * i + 3], aA);
            aB = hfma2u(hv.x, w4.x, aB); aB = hfma2u(hv.y, w4.y, aB);
            aB = hfma2u(hv.z, w4.z, aB); aB = hfma2u(hv.w, w4.w, aB);
        }
        part[rA * 2 + q] = xA + h2sum(aA);
        part[rB * 2 + q] = xB + h2sum(aB);
        __syncthreads();
        if (t < 256) {
            const int u = t;
            float gi = part[u * 2]          + part[u * 2 + 1];
            float gf = part[(256 + u) * 2]  + part[(256 + u) * 2 + 1];
            float gg = part[(512 + u) * 2]  + part[(512 + u) * 2 + 1];
            float go = part[(768 + u) * 2]  + part[(768 + u) * 2 + 1];
            c = sig_(gf) * c + sig_(gi) * tanh_(gg);
            float h = sig_(go) * tanh_(c);
            ((ushort*)hpq)[u] = __builtin_bit_cast(ushort, (_Float16)h);
            if (s >= out_start) out[HID_BASE + s * 384 + u] = h;
        }
        __syncthreads();
    }
}

// ---------- K5: logits + log_softmax, transposed store ----------
__global__ __launch_bounds__(64) void pos_logits(
    const float* __restrict__ wlin, const float* __restrict__ linb,
    float* __restrict__ out)
{
    const int word = blockIdx.x * 64 + threadIdx.x;
    const float4* hid = (const float4*)(out + HID_BASE + word * 384);
    float acc[50];
    #pragma unroll
    for (int tt = 0; tt < 50; ++tt) acc[tt] = linb[tt];
    for (int k4 = 0; k4 < 96; ++k4) {
        float4 hv = hid[k4];
        const float* w0 = wlin + (4 * k4) * 52;
        #pragma unroll
        for (int tt = 0; tt < 50; ++tt) acc[tt] += hv.x * w0[tt];
        #pragma unroll
        for (int tt = 0; tt < 50; ++tt) acc[tt] += hv.y * w0[52 + tt];
        #pragma unroll
        for (int tt = 0; tt < 50; ++tt) acc[tt] += hv.z * w0[104 + tt];
        #pragma unroll
        for (int tt = 0; tt < 50; ++tt) acc[tt] += hv.w * w0[156 + tt];
    }
    float m = acc[0];
    #pragma unroll
    for (int tt = 1; tt < 50; ++tt) m = fmaxf(m, acc[tt]);
    float ssum = 0.f;
    #pragma unroll
    for (int tt = 0; tt < 50; ++tt) ssum += __expf(acc[tt] - m);
    float lse = m + __logf(ssum);
    #pragma unroll
    for (int tt = 0; tt < 50; ++tt) out[tt * NW + word] = acc[tt] - lse;
}

// ---------- launch ----------
extern "C" void kernel_launch(void* const* d_in, const int* in_sizes, int n_in,
                              void* d_out, int out_size, void* d_ws, size_t ws_size,
                              hipStream_t stream)
{
    const int*   sentence  = (const int*)d_in[0];
    const int*   char_ids  = (const int*)d_in[1];
    const int*   char_lens = (const int*)d_in[2];
    const float* cemb = (const float*)d_in[3];
    const float* wemb = (const float*)d_in[4];
    const float* wihc = (const float*)d_in[5];
    const float* whhc = (const float*)d_in[6];
    const float* bihc = (const float*)d_in[7];
    const float* bhhc = (const float*)d_in[8];
    const float* wihw = (const float*)d_in[9];
    const float* whhw = (const float*)d_in[10];
    const float* bihw = (const float*)d_in[11];
    const float* bhhw = (const float*)d_in[12];
    const float* linW = (const float*)d_in[13];
    const float* linb = (const float*)d_in[14];
    float* out = (float*)d_out;
    char*  ws  = (char*)d_ws;

    float* Ep    = (float*)(ws + 0);                // 256 KB
    uint*  Wch   = (uint*) (ws + (256 << 10));      // 128 KB
    uint*  Wihw  = (uint*) (ws + (384 << 10));      // 256 KB
    uint*  WwR   = (uint*) (ws + (640 << 10));      // 384 KB (96*1024 dwords)
    uint*  WwL   = (uint*) (ws + (1024 << 10));     // 128 KB (8*1024 uint4)
    float* wlin  = (float*)(ws + (1280 << 10));     // ~80 KB
    ushort* Xw   = (ushort*)(ws + (2048 << 10));    // 32 MB

    pos_prep  <<<dim3(1230), dim3(256), 0, stream>>>(cemb, wihc, whhc, bihc, bhhc,
                                                     wihw, whhw, linW,
                                                     Ep, Wch, Wihw, WwR, WwL, wlin);
    pos_char  <<<dim3(256), dim3(1024), 0, stream>>>(char_ids, char_lens, Ep, Wch, out);
    pos_wordx <<<dim3(256), dim3(1024), 0, stream>>>(sentence, wemb, Wihw, bihw, bhhw, Xw);
    pos_word  <<<dim3(256), dim3(1024), 0, stream>>>(Xw, WwR, (const uint4*)WwL, out);
    pos_logits<<<dim3(256), dim3(64),  0, stream>>>(wlin, linb, out);
}

// Round 2
// 608.031 us; speedup vs baseline: 1.8656x; 1.8656x over previous
//
#include <hip/hip_runtime.h>
#include <hip/hip_fp16.h>

typedef unsigned int  uint;
typedef unsigned short ushort;
typedef _Float16 half8 __attribute__((ext_vector_type(8)));
typedef float f32x4 __attribute__((ext_vector_type(4)));

#define NW       16384            // words in sentence
#define HID_BASE (50*16384)       // d_out: [0,HID_BASE) = logp[t][s], then hidden[s][384]

// ---------- helpers ----------
__device__ __forceinline__ __half2 hfma2u(uint a, uint b, __half2 acc) {
    return __hfma2(__builtin_bit_cast(__half2, a), __builtin_bit_cast(__half2, b), acc);
}
__device__ __forceinline__ float h2sum(__half2 v) { return __low2float(v) + __high2float(v); }
__device__ __forceinline__ uint packf16(float a, float b) {
    __half2 v = __floats2half2_rn(a, b);
    return __builtin_bit_cast(uint, v);
}
__device__ __forceinline__ ushort f16bits(float x) {
    return __builtin_bit_cast(ushort, (_Float16)x);
}
__device__ __forceinline__ float sig_(float x)  { return 1.0f / (1.0f + __expf(-x)); }
__device__ __forceinline__ float tanh_(float x) {
    x = fminf(fmaxf(x, -30.f), 30.f);
    float e = __expf(2.f * x);
    return (e - 1.f) / (e + 1.f);
}

// ---------- K1: prep ----------
// sections (flat gid):
//  A: 65536  Ep[c][u*4+g] = relu(cemb[c]) . wih_c[gate] + bihc+bhhc,  gate = g*128+u
//  B: 65536  WchT[col][k] f16 = whh_c[gate(col)][k], col = u*4+g (gate-permuted, B^T for MFMA)
//  C: 65536  Wihw[r][kk]  f16-pair of wih_w[r][2kk..]
//  D: 131072 word whh f16 pairs, split into reg blob [j<96][1024] + lds blob
//  E: 19968  wlin[k][52] = lin_W[t][k] transposed (pad to 52)
__global__ __launch_bounds__(256) void pos_prep(
    const float* __restrict__ cemb,  const float* __restrict__ wihc,
    const float* __restrict__ whhc,  const float* __restrict__ bihc,
    const float* __restrict__ bhhc,  const float* __restrict__ wihw,
    const float* __restrict__ whhw,  const float* __restrict__ linW,
    float* __restrict__ Ep, ushort* __restrict__ WchT, uint* __restrict__ Wihw,
    uint* __restrict__ WwR, uint* __restrict__ WwL, float* __restrict__ wlin)
{
    int gid = blockIdx.x * 256 + threadIdx.x;
    if (gid < 65536) {
        int c = gid >> 9, p = gid & 511;
        int uu = p >> 2, gs = p & 3;
        int gate = gs * 128 + uu;
        float acc = bihc[gate] + bhhc[gate];
        const float* er = cemb + c * 64;
        const float* wr = wihc + gate * 64;
        #pragma unroll 16
        for (int k = 0; k < 64; ++k) acc += fmaxf(er[k], 0.f) * wr[k];
        Ep[c * 512 + p] = acc;
        return;
    }
    gid -= 65536;
    if (gid < 65536) {
        int col = gid >> 7, k = gid & 127;
        int gate = ((col & 3) << 7) + (col >> 2);
        WchT[gid] = f16bits(whhc[gate * 128 + k]);
        return;
    }
    gid -= 65536;
    if (gid < 65536) {
        int r = gid >> 6, kk = gid & 63;
        Wihw[gid] = packf16(wihw[r * 128 + 2 * kk], wihw[r * 128 + 2 * kk + 1]);
        return;
    }
    gid -= 65536;
    if (gid < 131072) {
        int j = gid >> 10, t = gid & 1023;
        int q = t >> 9, rb = t & 511;
        int row = (j < 64) ? rb : (512 + rb);
        int kk = j & 63;
        int k0 = q * 128 + 2 * kk;
        uint val = packf16(whhw[row * 256 + k0], whhw[row * 256 + k0 + 1]);
        if (j < 96) WwR[j * 1024 + t] = val;
        else { int jj = j - 96; WwL[((jj >> 2) * 1024 + t) * 4 + (jj & 3)] = val; }
        return;
    }
    gid -= 131072;
    if (gid < 384 * 52) {
        int k = gid / 52, tt = gid % 52;
        wlin[gid] = (tt < 50) ? linW[tt * 384 + k] : 0.f;
    }
}

// ---------- K2: char LSTM via MFMA 16x16x32 f16 ----------
// 256 WGs x 1024 thr (16 waves). WG = 64 words. Wave w owns gate-cols [32w,32w+32)
// = units [8w,8w+8). h in double-buffered XOR-swizzled LDS [64][128] f16.
// Whh B-fragments register-resident for all 16 steps. c-state in registers.
__global__ __launch_bounds__(1024) void pos_char(
    const int* __restrict__ char_ids, const int* __restrict__ char_lens,
    const float* __restrict__ Ep, const ushort* __restrict__ WchT,
    float* __restrict__ out)
{
    __shared__ ushort hbuf[2][64 * 128];   // 2 x 16 KB, swizzled: byte = w*256 + (2u ^ ((w&7)<<4))
    const int tid  = threadIdx.x;
    const int lane = tid & 63;
    const int wv   = tid >> 6;            // 0..15
    const int wg0  = blockIdx.x * 64;

    // zero both h buffers
    {
        uint* z = (uint*)&hbuf[0][0];
        for (int i = tid; i < 8192; i += 1024) z[i] = 0;
    }

    // B fragments (Whh^T, gate-permuted), held in VGPRs across all steps.
    half8 Bf[2][4];
    #pragma unroll
    for (int n = 0; n < 2; ++n)
    #pragma unroll
    for (int kk = 0; kk < 4; ++kk) {
        int col = 32 * wv + 16 * n + (lane & 15);
        int k0  = 32 * kk + 8 * (lane >> 4);
        Bf[n][kk] = *(const half8*)(WchT + col * 128 + k0);
    }

    // per-m word info (lane owns word wl[m] after the quad transpose)
    int wl[4], len1[4];
    #pragma unroll
    for (int m = 0; m < 4; ++m) {
        wl[m]   = 16 * m + 4 * (lane >> 4) + (lane & 3);
        len1[m] = char_lens[wg0 + wl[m]] - 1;
    }
    const int unit0 = 8 * wv + ((lane >> 2) & 3);  // + 4n
    float cst[4][2];
    #pragma unroll
    for (int m = 0; m < 4; ++m) { cst[m][0] = 0.f; cst[m][1] = 0.f; }

    const int swzA = (lane & 7) << 4;
    const int l1 = lane & 1, l2 = lane & 2;
    __syncthreads();

    for (int step = 0; step < 16; ++step) {
        const ushort* hprev = hbuf[step & 1];
        ushort* hnext = hbuf[(step & 1) ^ 1];
        // prefetch char ids for this step (hide gather latency under MFMA)
        int cid[4];
        #pragma unroll
        for (int m = 0; m < 4; ++m) cid[m] = char_ids[(wg0 + wl[m]) * 16 + step];

        #pragma unroll
        for (int m = 0; m < 4; ++m) {
            // A fragments: h[16m+(l&15)][32kk+8*(l>>4) .. +8]
            half8 Af[4];
            const int rowb = (16 * m + (lane & 15)) * 256;
            #pragma unroll
            for (int kk = 0; kk < 4; ++kk) {
                int cb = (64 * kk + 16 * (lane >> 4)) ^ swzA;
                Af[kk] = *(const half8*)((const char*)hprev + rowb + cb);
            }
            const float4* ev = (const float4*)Ep + cid[m] * 128;
            #pragma unroll
            for (int n = 0; n < 2; ++n) {
                f32x4 acc = {0.f, 0.f, 0.f, 0.f};
                #pragma unroll
                for (int kk = 0; kk < 4; ++kk)
                    acc = __builtin_amdgcn_mfma_f32_16x16x32_f16(Af[kk], Bf[n][kk], acc, 0, 0, 0);
                // 4x4 transpose within lane quads: lane gets (i,f,g,o) of its word
                float v0 = acc[0], v1 = acc[1], v2 = acc[2], v3 = acc[3];
                float a = l1 ? v0 : v1, b = l1 ? v2 : v3;
                a = __shfl_xor(a, 1); b = __shfl_xor(b, 1);
                if (l1) { v0 = a; v2 = b; } else { v1 = a; v3 = b; }
                a = l2 ? v0 : v2; b = l2 ? v1 : v3;
                a = __shfl_xor(a, 2); b = __shfl_xor(b, 2);
                if (l2) { v0 = a; v1 = b; } else { v2 = a; v3 = b; }

                const int un = unit0 + 4 * n;
                const float4 e = ev[un];
                float gi = v0 + e.x, gf = v1 + e.y, gg = v2 + e.z, go = v3 + e.w;
                float c = sig_(gf) * cst[m][n] + sig_(gi) * tanh_(gg);
                cst[m][n] = c;
                float h = sig_(go) * tanh_(c);
                int off = wl[m] * 256 + ((2 * un) ^ ((wl[m] & 7) << 4));
                *(ushort*)((char*)hnext + off) = f16bits(h);
                if (step == len1[m])
                    out[HID_BASE + (wg0 + wl[m]) * 384 + 256 + un] = h;
            }
        }
        __syncthreads();
    }
}

// ---------- K3: word x-part GEMM: Xw[s][r] = relu(wemb[sent[s]]).wih_w[r] + bihw+bhhw ----------
__global__ __launch_bounds__(1024) void pos_wordx(
    const int* __restrict__ sentence, const float* __restrict__ wemb,
    const uint* __restrict__ Wihw, const float* __restrict__ bihw,
    const float* __restrict__ bhhw, ushort* __restrict__ Xw)
{
    const int tid  = threadIdx.x;
    const int lane = tid & 63;
    const int wv   = __builtin_amdgcn_readfirstlane(tid >> 6); // 0..15, gates wv*64..+64
    const int word = blockIdx.x * 64 + lane;
    const int sid  = sentence[word];
    const float4* xr = (const float4*)(wemb + sid * 128);
    uint xp[64];
    #pragma unroll
    for (int i = 0; i < 32; ++i) {
        float4 v = xr[i];
        xp[2 * i]     = packf16(fmaxf(v.x, 0.f), fmaxf(v.y, 0.f));
        xp[2 * i + 1] = packf16(fmaxf(v.z, 0.f), fmaxf(v.w, 0.f));
    }
    const uint4* Wq = (const uint4*)Wihw;
    const __half2 hz = __float2half2_rn(0.f);
    for (int rr = 0; rr < 64; ++rr) {
        const int r = wv * 64 + rr;
        const uint4* wrow = Wq + r * 16;  // uniform
        __half2 a = hz;
        #pragma unroll
        for (int k4 = 0; k4 < 16; ++k4) {
            uint4 w4 = wrow[k4];
            a = hfma2u(xp[4 * k4 + 0], w4.x, a);
            a = hfma2u(xp[4 * k4 + 1], w4.y, a);
            a = hfma2u(xp[4 * k4 + 2], w4.z, a);
            a = hfma2u(xp[4 * k4 + 3], w4.w, a);
        }
        float acc = bihw[r] + bhhw[r] + h2sum(a);
        Xw[word * 1024 + r] = f16bits(acc);
    }
}

// ---------- K4: word LSTM, chunk-parallel with 64-step warmup ----------
__global__ __launch_bounds__(1024) void pos_word(
    const ushort* __restrict__ Xw, const uint* __restrict__ WwR,
    const uint4* __restrict__ WwL, float* __restrict__ out)
{
    __shared__ uint4 wlds[8 * 1024];   // 128 KB
    __shared__ float part[2048];       // 8 KB
    __shared__ __align__(16) uint hpq[128]; // h as 128 f16-pairs
    const int t  = threadIdx.x;
    const int q  = __builtin_amdgcn_readfirstlane(t >> 9);
    const int rb = t & 511;
    const int rA = rb, rB = 512 + rb;
    uint wr[96];
    #pragma unroll
    for (int j = 0; j < 96; ++j) wr[j] = WwR[j * 1024 + t];
    #pragma unroll
    for (int g = 0; g < 8; ++g) wlds[g * 1024 + t] = WwL[g * 1024 + t];
    if (t < 128) hpq[t] = 0;
    float c = 0.f;
    __syncthreads();
    const int out_start = blockIdx.x * 64;
    const int s0   = (out_start >= 64) ? (out_start - 64) : 0;
    const int send = out_start + 64;
    const uint4* hq = (const uint4*)hpq + q * 16;
    const __half2 hz = __float2half2_rn(0.f);
    for (int s = s0; s < send; ++s) {
        float xA = 0.f, xB = 0.f;
        if (q == 0) {
            xA = (float)__builtin_bit_cast(_Float16, Xw[s * 1024 + rA]);
            xB = (float)__builtin_bit_cast(_Float16, Xw[s * 1024 + rB]);
        }
        __half2 aA = hz, aB = hz;
        #pragma unroll
        for (int i = 0; i < 8; ++i) {
            uint4 hv = hq[i];
            aA = hfma2u(hv.x, wr[4 * i + 0], aA); aA = hfma2u(hv.y, wr[4 * i + 1], aA);
            aA = hfma2u(hv.z, wr[4 * i + 2], aA); aA = hfma2u(hv.w, wr[4 * i + 3], aA);
            aB = hfma2u(hv.x, wr[64 + 4 * i + 0], aB); aB = hfma2u(hv.y, wr[64 + 4 * i + 1], aB);
            aB = hfma2u(hv.z, wr[64 + 4 * i + 2], aB); aB = hfma2u(hv.w, wr[64 + 4 * i + 3], aB);
        }
        #pragma unroll
        for (int i = 8; i < 16; ++i) {
            uint4 hv = hq[i];
            uint4 w4 = wlds[(i - 8) * 1024 + t];
            aA = hfma2u(hv.x, wr[4 * i + 0], aA); aA = hfma2u(hv.y, wr[4 * i + 1], aA);
            aA = hfma2u(hv.z, wr[4 * i + 2], aA); aA = hfma2u(hv.w, wr[4 * i + 3], aA);
            aB = hfma2u(hv.x, w4.x, aB); aB = hfma2u(hv.y, w4.y, aB);
            aB = hfma2u(hv.z, w4.z, aB); aB = hfma2u(hv.w, w4.w, aB);
        }
        part[rA * 2 + q] = xA + h2sum(aA);
        part[rB * 2 + q] = xB + h2sum(aB);
        __syncthreads();
        if (t < 256) {
            const int u = t;
            float gi = part[u * 2]          + part[u * 2 + 1];
            float gf = part[(256 + u) * 2]  + part[(256 + u) * 2 + 1];
            float gg = part[(512 + u) * 2]  + part[(512 + u) * 2 + 1];
            float go = part[(768 + u) * 2]  + part[(768 + u) * 2 + 1];
            c = sig_(gf) * c + sig_(gi) * tanh_(gg);
            float h = sig_(go) * tanh_(c);
            ((ushort*)hpq)[u] = f16bits(h);
            if (s >= out_start) out[HID_BASE + s * 384 + u] = h;
        }
        __syncthreads();
    }
}

// ---------- K5: logits + log_softmax, transposed store ----------
__global__ __launch_bounds__(64) void pos_logits(
    const float* __restrict__ wlin, const float* __restrict__ linb,
    float* __restrict__ out)
{
    const int word = blockIdx.x * 64 + threadIdx.x;
    const float4* hid = (const float4*)(out + HID_BASE + word * 384);
    float acc[50];
    #pragma unroll
    for (int tt = 0; tt < 50; ++tt) acc[tt] = linb[tt];
    for (int k4 = 0; k4 < 96; ++k4) {
        float4 hv = hid[k4];
        const float* w0 = wlin + (4 * k4) * 52;
        #pragma unroll
        for (int tt = 0; tt < 50; ++tt) acc[tt] += hv.x * w0[tt];
        #pragma unroll
        for (int tt = 0; tt < 50; ++tt) acc[tt] += hv.y * w0[52 + tt];
        #pragma unroll
        for (int tt = 0; tt < 50; ++tt) acc[tt] += hv.z * w0[104 + tt];
        #pragma unroll
        for (int tt = 0; tt < 50; ++tt) acc[tt] += hv.w * w0[156 + tt];
    }
    float m = acc[0];
    #pragma unroll
    for (int tt = 1; tt < 50; ++tt) m = fmaxf(m, acc[tt]);
    float ssum = 0.f;
    #pragma unroll
    for (int tt = 0; tt < 50; ++tt) ssum += __expf(acc[tt] - m);
    float lse = m + __logf(ssum);
    #pragma unroll
    for (int tt = 0; tt < 50; ++tt) out[tt * NW + word] = acc[tt] - lse;
}

// ---------- launch ----------
extern "C" void kernel_launch(void* const* d_in, const int* in_sizes, int n_in,
                              void* d_out, int out_size, void* d_ws, size_t ws_size,
                              hipStream_t stream)
{
    const int*   sentence  = (const int*)d_in[0];
    const int*   char_ids  = (const int*)d_in[1];
    const int*   char_lens = (const int*)d_in[2];
    const float* cemb = (const float*)d_in[3];
    const float* wemb = (const float*)d_in[4];
    const float* wihc = (const float*)d_in[5];
    const float* whhc = (const float*)d_in[6];
    const float* bihc = (const float*)d_in[7];
    const float* bhhc = (const float*)d_in[8];
    const float* wihw = (const float*)d_in[9];
    const float* whhw = (const float*)d_in[10];
    const float* bihw = (const float*)d_in[11];
    const float* bhhw = (const float*)d_in[12];
    const float* linW = (const float*)d_in[13];
    const float* linb = (const float*)d_in[14];
    float* out = (float*)d_out;
    char*  ws  = (char*)d_ws;

    float*  Ep    = (float*)(ws + 0);                // 256 KB
    ushort* WchT  = (ushort*)(ws + (256 << 10));     // 128 KB
    uint*   Wihw  = (uint*) (ws + (384 << 10));      // 256 KB
    uint*   WwR   = (uint*) (ws + (640 << 10));      // 384 KB
    uint*   WwL   = (uint*) (ws + (1024 << 10));     // 128 KB
    float*  wlin  = (float*)(ws + (1280 << 10));     // ~80 KB
    ushort* Xw    = (ushort*)(ws + (2048 << 10));    // 32 MB

    pos_prep  <<<dim3(1358), dim3(256), 0, stream>>>(cemb, wihc, whhc, bihc, bhhc,
                                                     wihw, whhw, linW,
                                                     Ep, WchT, Wihw, WwR, WwL, wlin);
    pos_char  <<<dim3(256), dim3(1024), 0, stream>>>(char_ids, char_lens, Ep, WchT, out);
    pos_wordx <<<dim3(256), dim3(1024), 0, stream>>>(sentence, wemb, Wihw, bihw, bhhw, Xw);
    pos_word  <<<dim3(256), dim3(1024), 0, stream>>>(Xw, WwR, (const uint4*)WwL, out);
    pos_logits<<<dim3(256), dim3(64),  0, stream>>>(wlin, linb, out);
}